// Round 8
// baseline (184.338 us; speedup 1.0000x reference)
//
#include <hip/hip_runtime.h>
#include <hip/hip_bf16.h>
#include <math.h>

#define BB 2
#define SS 2048
#define DD 2048
#define NR (BB*(SS-1))      // 4094 valid rows
#define NRP 4096            // padded rows
#define MT_LD 768           // compact proj layout: [p1 512 | p2 128 | p3 32 | pad]
#define MT_P2 512
#define MT_P3 640

#define L2E 1.4426950408889634f
#define LN2F 0.6931471805599453f
#define LSE_SHIFT 4.0f
#define LSE_NC (-LSE_SHIFT * L2E)
#define WSCALE 16.0f        // fp8 weight pre-scale (avoids e4m3 subnormals at |w|~0.02)
#define WINV   0.0625f

typedef short  bh8   __attribute__((ext_vector_type(8)));
typedef float  f32x4 __attribute__((ext_vector_type(4)));
typedef long   l64x2 __attribute__((ext_vector_type(2)));   // 16 B = two fp8 MFMA operands

__device__ inline float bfl(unsigned short b) { return __uint_as_float(((unsigned)b) << 16); }
__device__ inline float expsh(float v) { return __builtin_amdgcn_exp2f(fmaf(v, L2E, LSE_NC)); }

__device__ inline float block_sum256(float v) {
    __shared__ float tmp[4];
    #pragma unroll
    for (int o = 32; o > 0; o >>= 1) v += __shfl_down(v, o, 64);
    int lane = threadIdx.x & 63, w = threadIdx.x >> 6;
    if (lane == 0) tmp[w] = v;
    __syncthreads();
    float r = tmp[0] + tmp[1] + tmp[2] + tmp[3];
    __syncthreads();
    return r;
}

// pack 4 floats -> 4 e4m3 bytes (HW cvt, saturating)
__device__ inline unsigned pack_fp8x4(float a, float b, float c, float d) {
    unsigned r = 0;
    r = __builtin_amdgcn_cvt_pk_fp8_f32(a, b, r, false);   // bytes 0-1
    r = __builtin_amdgcn_cvt_pk_fp8_f32(c, d, r, true);    // bytes 2-3
    return r;
}

// ================= stage A: LN + weight casts + compaction/init, ONE launch =================
struct CastSegs {
    const float* src[7];
    void* dst[7];
    int n_src[7];
    int n_tot[7];
    int b0[7];
    int isfp8[7];       // 1: fp8 e4m3 scaled by WSCALE; 0: bf16 scaled by scl[]
    float scl[7];       // bf16-path scale (1.0, or L2E for t3_w2 exp2-fold)
};
struct AParams {
    const float* x; const float* gamma; const float* beta;
    unsigned char* h8;                                 // fp8 h [4096][2048]
    CastSegs sg; int castBlocks;
    const int* targets;
    int *relH;
    int *cnt;                                          // [0]=n1 [1]=n2 [2]=n3 (memset 0)
    int *rlist1, *rlist2, *rlist3;                     // compact -> original row
    int *cidx1, *cidx2, *cidx3;                        // original row -> compact
    int *rel1c, *rel2c, *rel3c;                        // compact target cols
    float *S0, *S1c, *S2c, *out;
};

__global__ __launch_bounds__(256) void stageA(AParams p) {
    int blk = blockIdx.x, tid = threadIdx.x;
    if (blk < NRP) {                                   // ---- LayerNorm role -> fp8 h ----
        int n = blk;
        unsigned char* hr = p.h8 + (size_t)n * DD;
        if (n >= NR) { *(uint2*)(hr + tid * 8) = make_uint2(0,0); return; }
        int b = n / (SS - 1), t = n % (SS - 1);
        const float4* xr = (const float4*)(p.x + (size_t)(b * SS + t) * DD);
        float4 a = xr[tid * 2];
        float4 c = xr[tid * 2 + 1];
        float sum = a.x + a.y + a.z + a.w + c.x + c.y + c.z + c.w;
        sum = block_sum256(sum);
        float mu = sum * (1.0f / DD);
        float d[8] = {a.x-mu, a.y-mu, a.z-mu, a.w-mu, c.x-mu, c.y-mu, c.z-mu, c.w-mu};
        float sq = 0.f;
        #pragma unroll
        for (int i = 0; i < 8; ++i) sq += d[i] * d[i];
        sq = block_sum256(sq);
        float rstd = rsqrtf(sq * (1.0f / DD) + 1e-5f);
        const float4* g4 = (const float4*)p.gamma;
        const float4* be4 = (const float4*)p.beta;
        float4 g1 = g4[tid*2], g2 = g4[tid*2+1];
        float4 b1 = be4[tid*2], b2 = be4[tid*2+1];
        float gg[8] = {g1.x,g1.y,g1.z,g1.w,g2.x,g2.y,g2.z,g2.w};
        float bb[8] = {b1.x,b1.y,b1.z,b1.w,b2.x,b2.y,b2.z,b2.w};
        float o[8];
        #pragma unroll
        for (int i = 0; i < 8; ++i) o[i] = d[i] * rstd * gg[i] + bb[i];
        uint2 pk;
        pk.x = pack_fp8x4(o[0], o[1], o[2], o[3]);
        pk.y = pack_fp8x4(o[4], o[5], o[6], o[7]);
        *(uint2*)(hr + tid * 8) = pk;
        return;
    }
    blk -= NRP;
    if (blk < p.castBlocks) {                          // ---- weight cast role ----
        int k = 0;
        #pragma unroll
        for (int i = 1; i < 7; ++i) if (blk >= p.sg.b0[i]) k = i;
        int i4 = (blk - p.sg.b0[k]) * 1024 + tid * 4;
        if (i4 >= p.sg.n_tot[k]) return;
        float4 v = make_float4(0.f,0.f,0.f,0.f);
        if (i4 < p.sg.n_src[k]) v = *(const float4*)(p.sg.src[k] + i4);
        if (p.sg.isfp8[k]) {
            unsigned pk = pack_fp8x4(v.x * WSCALE, v.y * WSCALE, v.z * WSCALE, v.w * WSCALE);
            *(unsigned*)((unsigned char*)p.sg.dst[k] + i4) = pk;
        } else {
            float sc = p.sg.scl[k];
            __align__(8) __hip_bfloat16 o[4] = {
                __float2bfloat16(v.x * sc), __float2bfloat16(v.y * sc),
                __float2bfloat16(v.z * sc), __float2bfloat16(v.w * sc)};
            *(uint2*)((__hip_bfloat16*)p.sg.dst[k] + i4) = *(uint2*)o;
        }
        return;
    }
    blk -= p.castBlocks;                               // ---- init + compaction role ----
    int n = blk * 256 + tid;
    if (n >= NRP) return;
    int lbl = -1;
    if (n < NR) {
        int b = n / (SS - 1), t = n % (SS - 1);
        lbl = p.targets[b * SS + t + 1];
    }
    bool v = n < NR;
    p.relH[n] = v ? (lbl < 1000 ? lbl : 999) : -1;
    if (v) {                                           // compact per-cluster row lists
        if (lbl >= 1000 && lbl < 2000) {
            int ci = atomicAdd(&p.cnt[0], 1);
            p.rlist1[ci] = n; p.cidx1[n] = ci;
            int r1 = lbl - 1000; p.rel1c[ci] = r1 > 999 ? 999 : r1;
        } else if (lbl >= 2000 && lbl < 5000) {
            int ci = atomicAdd(&p.cnt[1], 1);
            p.rlist2[ci] = n; p.cidx2[n] = ci;
            int r2 = lbl - 2000; p.rel2c[ci] = r2 > 2999 ? 2999 : r2;
        } else if (lbl >= 5000) {
            int ci = atomicAdd(&p.cnt[2], 1);
            p.rlist3[ci] = n; p.cidx3[n] = ci;
            int r3 = lbl - 5000; p.rel3c[ci] = r3 > 26999 ? 26999 : r3;
        }
    }
    p.S0[n] = 0.f; p.S1c[n] = 0.f; p.S2c[n] = 0.f;
    if (n == 0) p.out[0] = 0.f;
}

// ================= stage B: mega GEMM fp8, BK=64, R6 2-buffer loop =================
// Head (bx<8): BM=32, y in [0,128) -> 1024 blocks (~4.3/CU) for TLP latency hiding.
// Proj (bx>=8): BM=64 verbatim R6, y<64; p1/p2 compact-gathered via rlist, early-exit.
__global__ __launch_bounds__(256) void megaF(
        const unsigned char* __restrict__ A,           // h8 [4096][2048] fp8
        const unsigned char* __restrict__ W,           // w1cat8 [1792][2048] fp8 (x16)
        __hip_bfloat16* __restrict__ megaT,            // [4096][768]
        const int* __restrict__ relH,
        const int* __restrict__ cnt,
        const int* __restrict__ rlist1, const int* __restrict__ rlist2,
        float* __restrict__ S0, float* __restrict__ aux) {
    __shared__ __align__(16) unsigned char smF[2][12288];   // [buf][As | Ws at +4096]
    int tid = threadIdx.x, wv = tid >> 6, lane = tid & 63;
    int bx = blockIdx.x;
    int sr = lane >> 2;                                // row within 16-row chunk
    int kp = (((lane & 3) ^ (sr & 3)) * 16);           // swizzled byte slot within 64B row
    int mrow = lane & 15;
    int qx = (((lane >> 4) ^ (lane & 3)) * 16);        // swizzled frag b128 byte offset

    if (bx < 8) {
        // ================= HEAD path: BM=32 =================
        int row0 = blockIdx.y * 32, col0 = bx * 128;
        int wrow = (wv >> 1) * 16, wcol = (wv & 1) * 64;
        f32x4 acc[4];
        #pragma unroll
        for (int j = 0; j < 4; ++j) acc[j] = (f32x4){0.f,0.f,0.f,0.f};
        const unsigned char* gabase = A + (size_t)(row0 + wv * 16 + sr) * DD + kp;

        auto stage = [&](int buf, int k0) {
            if (wv < 2) {                              // A: 2 chunks of 16 rows (2 KB)
                void* la = (char*)&smF[buf][0] + wv * 1024 + lane * 16;
                __builtin_amdgcn_global_load_lds(
                    (const __attribute__((address_space(1))) void*)(gabase + k0),
                    (__attribute__((address_space(3))) void*)la, 16, 0, 0);
            }
            #pragma unroll
            for (int i = 0; i < 2; ++i) {              // W: 8 chunks of 16 rows (8 KB)
                int chunk = wv * 2 + i;
                int r = chunk * 16 + sr;
                const void* gw = W + (size_t)(col0 + r) * DD + k0 + kp;
                void* lw = (char*)&smF[buf][4096] + chunk * 1024 + lane * 16;
                __builtin_amdgcn_global_load_lds(
                    (const __attribute__((address_space(1))) void*)gw,
                    (__attribute__((address_space(3))) void*)lw, 16, 0, 0);
            }
        };

        stage(0, 0);
        asm volatile("s_waitcnt vmcnt(0)" ::: "memory");
        __builtin_amdgcn_s_barrier();
        __builtin_amdgcn_sched_barrier(0);
        int cur = 0;
        for (int k0 = 0; k0 < DD; k0 += 64) {
            if (k0 + 64 < DD) stage(cur ^ 1, k0 + 64);
            const unsigned char* As = &smF[cur][0];
            const unsigned char* Ws = &smF[cur][4096];
            l64x2 af, bfr[4];
            af = *(const l64x2*)(As + (wrow + mrow) * 64 + qx);
            #pragma unroll
            for (int u = 0; u < 4; ++u)
                bfr[u] = *(const l64x2*)(Ws + (wcol + u*16 + mrow) * 64 + qx);
            #pragma unroll
            for (int s = 0; s < 2; ++s)
                #pragma unroll
                for (int j = 0; j < 4; ++j)
                    acc[j] = __builtin_amdgcn_mfma_f32_16x16x32_fp8_fp8(
                        af[s], bfr[j][s], acc[j], 0, 0, 0);
            asm volatile("s_waitcnt vmcnt(0) lgkmcnt(0)" ::: "memory");
            __builtin_amdgcn_s_barrier();
            __builtin_amdgcn_sched_barrier(0);
            cur ^= 1;
        }
        int ccol = lane & 15, g = lane >> 4;
        int grs[4], rh[4];
        float ps[4];
        #pragma unroll
        for (int r = 0; r < 4; ++r) {
            grs[r] = row0 + wrow + g*4 + r;
            rh[r] = relH[grs[r]];
            ps[r] = 0.f;
        }
        #pragma unroll
        for (int j = 0; j < 4; ++j) {
            int gc = col0 + wcol + j*16 + ccol;
            bool inr = gc < 1003;
            #pragma unroll
            for (int r = 0; r < 4; ++r) {
                float v = acc[j][r] * WINV;
                if (gc == rh[r]) aux[grs[r]*8 + 0] = v;
                if (gc >= 1000 && gc < 1003) aux[grs[r]*8 + 2 + (gc - 1000)] = v;
                ps[r] += inr ? expsh(v) : 0.f;
            }
        }
        #pragma unroll
        for (int off = 1; off < 16; off <<= 1)
            #pragma unroll
            for (int r = 0; r < 4; ++r) ps[r] += __shfl_xor(ps[r], off, 64);
        if (ccol == 0)
            #pragma unroll
            for (int r = 0; r < 4; ++r) atomicAdd(&S0[grs[r]], ps[r]);
        return;
    }

    // ================= PROJ path: BM=64, verbatim R6 =================
    if (blockIdx.y >= 64) return;
    int row0 = blockIdx.y * 64, col0 = bx * 128;
    const int* rl = nullptr; int nrow = NRP;
    if (bx >= 8 && bx < 12) { rl = rlist1; nrow = cnt[0]; if (row0 >= nrow) return; }
    else if (bx == 12)      { rl = rlist2; nrow = cnt[1]; if (row0 >= nrow) return; }
    int wrow = (wv >> 1) * 32, wcol = (wv & 1) * 64;
    f32x4 acc[2][4];
    #pragma unroll
    for (int i = 0; i < 2; ++i)
        #pragma unroll
        for (int j = 0; j < 4; ++j) acc[i][j] = (f32x4){0.f,0.f,0.f,0.f};

    int ar = row0 + wv * 16 + sr;
    int orow = rl ? rl[ar < nrow ? ar : nrow - 1] : ar;
    const unsigned char* gabase = A + (size_t)orow * DD + kp;

    auto stage = [&](int buf, int k0) {
        {   // A: 4 chunks of 16 rows, one per wave
            void* la = (char*)&smF[buf][0] + wv * 1024 + lane * 16;
            __builtin_amdgcn_global_load_lds(
                (const __attribute__((address_space(1))) void*)(gabase + k0),
                (__attribute__((address_space(3))) void*)la, 16, 0, 0);
        }
        #pragma unroll
        for (int i = 0; i < 2; ++i) {                  // W: 8 chunks of 16 rows, two per wave
            int chunk = wv * 2 + i;
            int r = chunk * 16 + sr;
            const void* gw = W + (size_t)(col0 + r) * DD + k0 + kp;
            void* lw = (char*)&smF[buf][4096] + chunk * 1024 + lane * 16;
            __builtin_amdgcn_global_load_lds(
                (const __attribute__((address_space(1))) void*)gw,
                (__attribute__((address_space(3))) void*)lw, 16, 0, 0);
        }
    };

    stage(0, 0);
    asm volatile("s_waitcnt vmcnt(0)" ::: "memory");
    __builtin_amdgcn_s_barrier();
    __builtin_amdgcn_sched_barrier(0);
    int cur = 0;
    for (int k0 = 0; k0 < DD; k0 += 64) {
        if (k0 + 64 < DD) stage(cur ^ 1, k0 + 64);     // issue next tile early
        const unsigned char* As = &smF[cur][0];
        const unsigned char* Ws = &smF[cur][4096];
        l64x2 af[2], bfr[4];
        #pragma unroll
        for (int u = 0; u < 2; ++u)
            af[u]  = *(const l64x2*)(As + (wrow + u*16 + mrow) * 64 + qx);
        #pragma unroll
        for (int u = 0; u < 4; ++u)
            bfr[u] = *(const l64x2*)(Ws + (wcol + u*16 + mrow) * 64 + qx);
        #pragma unroll
        for (int s = 0; s < 2; ++s)
            #pragma unroll
            for (int i = 0; i < 2; ++i)
                #pragma unroll
                for (int j = 0; j < 4; ++j)
                    acc[i][j] = __builtin_amdgcn_mfma_f32_16x16x32_fp8_fp8(
                        af[i][s], bfr[j][s], acc[i][j], 0, 0, 0);
        asm volatile("s_waitcnt vmcnt(0) lgkmcnt(0)" ::: "memory");
        __builtin_amdgcn_s_barrier();
        __builtin_amdgcn_sched_barrier(0);
        cur ^= 1;
    }
    int ccol = lane & 15, g = lane >> 4;
    int cb = col0 - 1024 + wcol;
    #pragma unroll
    for (int i = 0; i < 2; ++i) {
        size_t gr0 = row0 + wrow + i*16 + g*4;
        #pragma unroll
        for (int j = 0; j < 4; ++j) {
            size_t gc = cb + j*16 + ccol;
            #pragma unroll
            for (int r = 0; r < 4; ++r)
                megaT[(gr0 + r) * MT_LD + gc] = __float2bfloat16(acc[i][j][r] * WINV);
        }
    }
}

// ================= tail GEMM — compact rows DIRECT (megaT p1/p2 segments are compact) =======
__device__ void tail_gemm(const __hip_bfloat16* A, int lda,
        const __hip_bfloat16* W, int K, int bx, int by, int validCols,
        const int* relc, float* S, float* tgt, char* sm, int nrows) {
    __hip_bfloat16* As = (__hip_bfloat16*)sm;          // 4 KB
    __hip_bfloat16* Ws = (__hip_bfloat16*)(sm + 4096); // 8 KB
    int tid = threadIdx.x, wv = tid >> 6, lane = tid & 63;
    int row0 = by * 64, col0 = bx * 128;
    int wrow = (wv >> 1) * 32, wcol = (wv & 1) * 64;
    f32x4 acc[2][4];
    #pragma unroll
    for (int i = 0; i < 2; ++i)
        #pragma unroll
        for (int j = 0; j < 4; ++j) acc[i][j] = (f32x4){0.f,0.f,0.f,0.f};
    int sr = lane >> 2;
    int sk = (((lane & 3) ^ (sr & 3)) * 8);            // swizzled k-slot (elements; 8 bf16 = 16B)
    int mrow = lane & 15;
    int qx = (((lane >> 4) ^ (lane & 3)) * 16);        // swizzled frag b128 byte offset

    for (int k0 = 0; k0 < K; k0 += 32) {
        __syncthreads();
        #pragma unroll
        for (int i = 0; i < 3; ++i) {
            int c = wv * 3 + i;
            const __hip_bfloat16* gsrc;
            char* ldst;
            if (c < 4) {
                gsrc = A + (size_t)(row0 + c * 16 + sr) * lda + k0 + sk;
                ldst = (char*)As + c * 1024 + lane * 16;
            } else {
                int cw = c - 4;
                gsrc = W + (size_t)(col0 + cw * 16 + sr) * K + k0 + sk;
                ldst = (char*)Ws + cw * 1024 + lane * 16;
            }
            __builtin_amdgcn_global_load_lds(
                (const __attribute__((address_space(1))) void*)gsrc,
                (__attribute__((address_space(3))) void*)ldst, 16, 0, 0);
        }
        __syncthreads();
        bh8 af[2], bfr[4];
        #pragma unroll
        for (int t = 0; t < 2; ++t)
            af[t] = *(const bh8*)((const char*)As + (wrow + t*16 + mrow) * 64 + qx);
        #pragma unroll
        for (int t = 0; t < 4; ++t)
            bfr[t] = *(const bh8*)((const char*)Ws + (wcol + t*16 + mrow) * 64 + qx);
        #pragma unroll
        for (int i = 0; i < 2; ++i)
            #pragma unroll
            for (int j = 0; j < 4; ++j)
                acc[i][j] = __builtin_amdgcn_mfma_f32_16x16x32_bf16(af[i], bfr[j], acc[i][j], 0, 0, 0);
    }
    int ccol = lane & 15, g = lane >> 4;
    int grs[2][4], rh[2][4];
    float p[2][4];
    #pragma unroll
    for (int i = 0; i < 2; ++i)
        #pragma unroll
        for (int r = 0; r < 4; ++r) {
            grs[i][r] = row0 + wrow + i*16 + g*4 + r;
            rh[i][r] = grs[i][r] < nrows ? relc[grs[i][r]] : 0;
            p[i][r] = 0.f;
        }
    #pragma unroll
    for (int i = 0; i < 2; ++i)
        #pragma unroll
        for (int j = 0; j < 4; ++j) {
            int gc = col0 + wcol + j*16 + ccol;
            bool inr = gc < validCols;
            #pragma unroll
            for (int r = 0; r < 4; ++r) {
                float v = acc[i][j][r];
                if (gc == rh[i][r] && grs[i][r] < nrows) tgt[grs[i][r]] = v;
                p[i][r] += inr ? expsh(v) : 0.f;
            }
        }
    #pragma unroll
    for (int off = 1; off < 16; off <<= 1)
        #pragma unroll
        for (int i = 0; i < 2; ++i)
            #pragma unroll
            for (int r = 0; r < 4; ++r) p[i][r] += __shfl_xor(p[i][r], off, 64);
    if (ccol == 0)
        #pragma unroll
        for (int i = 0; i < 2; ++i)
            #pragma unroll
            for (int r = 0; r < 4; ++r)
                if (grs[i][r] < nrows) atomicAdd(&S[grs[i][r]], p[i][r]);
}

// ================= t3 partial: compact rows, 16 colsplits, 4-deep register prefetch ========
#define T3_TILES 1688            // 1688*16 == 27008
#define T3_SPLIT 16
#define T3_TPC   106             // ceil(1688/16)
__device__ void t3_partial_body(const __hip_bfloat16* megaT,
        const __hip_bfloat16* w2b, float* pS, const int* rlist3, int n3,
        int idx, int tid, float* red /*[4][64]*/) {
    int rg = idx >> 4, cs = idx & 15;      // rowgroup (64 compact rows), colsplit
    int wv = tid >> 6, lane = tid & 63;
    int q = lane >> 4, cm = lane & 15;
    int row0 = rg * 64;
    bh8 af[4];
    #pragma unroll
    for (int h = 0; h < 4; ++h) {
        int r = row0 + h*16 + cm;
        int orow = rlist3[r < n3 ? r : n3 - 1];
        af[h] = *(const bh8*)(megaT + (size_t)orow * MT_LD + MT_P3 + q * 8);
    }
    int tile0 = cs * T3_TPC;
    int tile1 = tile0 + T3_TPC; if (tile1 > T3_TILES) tile1 = T3_TILES;
    float s[4][4];
    #pragma unroll
    for (int h = 0; h < 4; ++h)
        #pragma unroll
        for (int r = 0; r < 4; ++r) s[h][r] = 0.f;
    // 4-deep prefetch (covers ~2x L2 latency; clamped addrs, over-prefetch never consumed)
    int ot = tile0 + wv;
    auto baddr = [&](int t) {
        int tc = t < tile1 ? t : tile1 - 1;
        return (const bh8*)(w2b + (size_t)(tc * 16 + cm) * 32 + q * 8);
    };
    bh8 p0 = *baddr(ot), p1 = *baddr(ot + 4), p2 = *baddr(ot + 8), p3 = *baddr(ot + 12);
    for (; ot < tile1; ot += 4) {
        bh8 bcur = p0;
        p0 = p1; p1 = p2; p2 = p3;
        int otn = ot + 16;
        if (otn < tile1)
            p3 = *(const bh8*)(w2b + (size_t)(otn * 16 + cm) * 32 + q * 8);
        f32x4 c[4];
        #pragma unroll
        for (int h = 0; h < 4; ++h)
            c[h] = __builtin_amdgcn_mfma_f32_16x16x32_bf16(af[h], bcur, (f32x4){0,0,0,0}, 0, 0, 0);
        #pragma unroll
        for (int h = 0; h < 4; ++h)
            #pragma unroll
            for (int r = 0; r < 4; ++r) s[h][r] += __builtin_amdgcn_exp2f(c[h][r]);
    }
    #pragma unroll
    for (int off = 1; off < 16; off <<= 1)
        #pragma unroll
        for (int h = 0; h < 4; ++h)
            #pragma unroll
            for (int r = 0; r < 4; ++r) s[h][r] += __shfl_xor(s[h][r], off, 64);
    if (cm == 0)
        #pragma unroll
        for (int h = 0; h < 4; ++h)
            #pragma unroll
            for (int r = 0; r < 4; ++r)
                red[wv * 64 + h*16 + q*4 + r] = s[h][r];
    __syncthreads();
    if (tid < 64)
        pS[(size_t)(row0 + tid) * T3_SPLIT + cs] =
            red[tid] + red[64 + tid] + red[128 + tid] + red[192 + tid];
}

__device__ void t3_gather_body(const __hip_bfloat16* megaT, const __hip_bfloat16* w2b,
        const int* rlist3, const int* rel3c, int n3, float* tt2c, int idx, int tid) {
    int ci = idx * 256 + tid;
    if (ci >= n3) return;
    int orow = rlist3[ci];
    int rc = rel3c[ci];
    const unsigned short* pa = (const unsigned short*)(megaT + (size_t)orow * MT_LD + MT_P3);
    const unsigned short* pw = (const unsigned short*)(w2b + (size_t)rc * 32);
    float acc = 0.f;
    #pragma unroll
    for (int k = 0; k < 32; ++k) acc += bfl(pa[k]) * bfl(pw[k]);
    tt2c[ci] = acc;               // scaled by L2E (w2b pre-scaled); final multiplies by ln2
}

// ================= stage C: merged fat kernel, sequential roles, compact-row early-exit ======
#define NT3 (64 * T3_SPLIT)      // 1024 worst-case
#define NT1 512                  // worst-case
#define NT2 1536                 // worst-case
#define NGATH 16                 // worst-case
__global__ __launch_bounds__(256) void fatC(const __hip_bfloat16* __restrict__ megaT,
        const __hip_bfloat16* __restrict__ t1w2b, const __hip_bfloat16* __restrict__ t2w2b,
        const __hip_bfloat16* __restrict__ w2b3,
        const int* __restrict__ cnt,
        const int* __restrict__ rlist3,
        const int* __restrict__ rel1c, const int* __restrict__ rel2c, const int* __restrict__ rel3c,
        float* __restrict__ S1c, float* __restrict__ S2c, float* __restrict__ pS3,
        float* __restrict__ tt0c, float* __restrict__ tt1c, float* __restrict__ tt2c) {
    __shared__ __align__(16) char sm[12288];
    int idx = blockIdx.x, tid = threadIdx.x;
    if (idx < NT3) {                                   // ---- t3 partial sums ----
        int n3 = cnt[2];
        if ((idx >> 4) * 64 >= n3) return;             // early-exit past compact rows
        t3_partial_body(megaT, w2b3, pS3, rlist3, n3, idx, tid, (float*)sm);
        return;
    }
    idx -= NT3;
    if (idx < NT1) {                                   // ---- t1 (compact rows ~128) ----
        int n1 = cnt[0];
        int by = idx / 8, bx = idx % 8;
        if (by * 64 >= n1) return;
        tail_gemm(megaT, MT_LD, t1w2b, 512, bx, by, 1000, rel1c, S1c, tt0c, sm, n1);
        return;
    }
    idx -= NT1;
    if (idx < NT2) {                                   // ---- t2 (compact rows ~384) ----
        int n2 = cnt[1];
        int by = idx / 24, bx = idx % 24;
        if (by * 64 >= n2) return;
        tail_gemm(megaT + MT_P2, MT_LD, t2w2b, 128, bx, by, 3000, rel2c, S2c, tt1c, sm, n2);
        return;
    }
    idx -= NT2;
    t3_gather_body(megaT, w2b3, rlist3, rel3c, cnt[2], tt2c, idx, tid);
}

// ================= stage E: final assembly =================
__global__ __launch_bounds__(256) void final_kernel(const float* __restrict__ aux,
        const int* __restrict__ targets,
        const float* __restrict__ S0, const float* __restrict__ S1c, const float* __restrict__ S2c,
        const float* __restrict__ pS3,
        const float* __restrict__ tt0c, const float* __restrict__ tt1c, const float* __restrict__ tt2c,
        const int* __restrict__ cidx1, const int* __restrict__ cidx2, const int* __restrict__ cidx3,
        float* __restrict__ out) {
    int n = blockIdx.x * 256 + threadIdx.x;
    float local = 0.f;
    if (n < NR) {
        int b = n / (SS - 1), t = n % (SS - 1);
        int lbl = targets[b * SS + t + 1];
        float lse = logf(S0[n]) + LSE_SHIFT;
        float o;
        if (lbl < 1000)      o = aux[n*8 + 0] - lse;
        else if (lbl < 2000) {
            int ci = cidx1[n];
            o = (aux[n*8 + 2] - lse) + (tt0c[ci] - (logf(S1c[ci]) + LSE_SHIFT));
        } else if (lbl < 5000) {
            int ci = cidx2[n];
            o = (aux[n*8 + 3] - lse) + (tt1c[ci] - (logf(S2c[ci]) + LSE_SHIFT));
        } else {
            int ci = cidx3[n];
            float S3 = 0.f;
            const float4* p4 = (const float4*)(pS3 + (size_t)ci * T3_SPLIT);
            #pragma unroll
            for (int c = 0; c < T3_SPLIT/4; ++c) {
                float4 v = p4[c];
                S3 += v.x + v.y + v.z + v.w;
            }
            S3 -= 8.0f;                                // pad cols: logit 0 -> exp2(0)=1 each
            o = (aux[n*8 + 4] - lse) + (tt2c[ci] * LN2F - logf(S3));
        }
        local = o;
    }
    local = block_sum256(local);
    if (threadIdx.x == 0) atomicAdd(out, -local / (float)NR);
}

extern "C" void kernel_launch(void* const* d_in, const int* in_sizes, int n_in,
                              void* d_out, int out_size, void* d_ws, size_t ws_size,
                              hipStream_t stream) {
    const float* x      = (const float*)d_in[0];
    const int*   targets= (const int*)d_in[1];
    const float* gamma  = (const float*)d_in[2];
    const float* beta   = (const float*)d_in[3];
    const float* head_w = (const float*)d_in[4];
    const float* t1_w1  = (const float*)d_in[5];
    const float* t1_w2  = (const float*)d_in[6];
    const float* t2_w1  = (const float*)d_in[7];
    const float* t2_w2  = (const float*)d_in[8];
    const float* t3_w1  = (const float*)d_in[9];
    const float* t3_w2  = (const float*)d_in[10];
    (void)in_sizes; (void)n_in; (void)out_size; (void)ws_size;

    char* base = (char*)d_ws;
    size_t off = 0;
    auto ab = [&](size_t nbytes) { char* p = base + off; off += (nbytes + 15) & ~(size_t)15; return p; };
    unsigned char* h8     = (unsigned char*)ab((size_t)NRP * DD);              // 8.4 MB fp8
    unsigned char* w1cat8 = (unsigned char*)ab((size_t)1792 * DD);             // 3.7 MB fp8
    __hip_bfloat16* megaT = (__hip_bfloat16*)ab((size_t)NRP * MT_LD * 2);      // 6.3 MB
    __hip_bfloat16* t1w2b = (__hip_bfloat16*)ab((size_t)1024 * 512 * 2);
    __hip_bfloat16* t2w2b = (__hip_bfloat16*)ab((size_t)3072 * 128 * 2);
    __hip_bfloat16* w2b3  = (__hip_bfloat16*)ab((size_t)27008 * 32 * 2);
    float* aux = (float*)ab((size_t)NRP * 8 * 4);
    float* pS3 = (float*)ab((size_t)NRP * T3_SPLIT * 4);
    float* S0  = (float*)ab(NRP * 4);
    float* S1c = (float*)ab(NRP * 4);
    float* S2c = (float*)ab(NRP * 4);
    int* relH  = (int*)ab(NRP * 4);
    int* cnt   = (int*)ab(4 * 4);
    int* rlist1= (int*)ab(NRP * 4);
    int* rlist2= (int*)ab(NRP * 4);
    int* rlist3= (int*)ab(NRP * 4);
    int* cidx1 = (int*)ab(NRP * 4);
    int* cidx2 = (int*)ab(NRP * 4);
    int* cidx3 = (int*)ab(NRP * 4);
    int* rel1c = (int*)ab(NRP * 4);
    int* rel2c = (int*)ab(NRP * 4);
    int* rel3c = (int*)ab(NRP * 4);
    float* tt0c= (float*)ab(NRP * 4);
    float* tt1c= (float*)ab(NRP * 4);
    float* tt2c= (float*)ab(NRP * 4);

    hipMemsetAsync(cnt, 0, 4 * 4, stream);             // zero compaction counters

    AParams p;
    p.x = x; p.gamma = gamma; p.beta = beta; p.h8 = h8;
    p.targets = targets;
    p.relH = relH;
    p.cnt = cnt;
    p.rlist1 = rlist1; p.rlist2 = rlist2; p.rlist3 = rlist3;
    p.cidx1 = cidx1; p.cidx2 = cidx2; p.cidx3 = cidx3;
    p.rel1c = rel1c; p.rel2c = rel2c; p.rel3c = rel3c;
    p.S0 = S0; p.S1c = S1c; p.S2c = S2c; p.out = (float*)d_out;
    const float* srcs[7] = {head_w, t1_w1, t2_w1, t3_w1, t1_w2, t2_w2, t3_w2};
    void* dsts[7] = {w1cat8, w1cat8 + (size_t)1024*2048, w1cat8 + (size_t)1536*2048,
                     w1cat8 + (size_t)1664*2048, t1w2b, t2w2b, w2b3};
    int nsrc[7] = {1003*2048, 512*2048, 128*2048, 32*2048, 1000*512, 3000*128, 27000*32};
    int ntot[7] = {1024*2048, 512*2048, 128*2048, 128*2048, 1024*512, 3072*128, 27008*32};
    int isf8[7] = {1, 1, 1, 1, 0, 0, 0};
    float scls[7] = {1.f, 1.f, 1.f, 1.f, 1.0f, 1.0f, L2E};   // t3_w2 pre-scaled for exp2-direct
    int blk = 0;
    for (int i = 0; i < 7; ++i) {
        p.sg.src[i] = srcs[i]; p.sg.dst[i] = dsts[i];
        p.sg.n_src[i] = nsrc[i]; p.sg.n_tot[i] = ntot[i];
        p.sg.isfp8[i] = isf8[i];
        p.sg.scl[i] = scls[i];
        p.sg.b0[i] = blk;
        blk += (ntot[i] + 1023) / 1024;
    }
    p.castBlocks = blk;

    stageA<<<NRP + blk + 16, 256, 0, stream>>>(p);
    megaF<<<dim3(14, 128), 256, 0, stream>>>(h8, w1cat8, megaT, relH, cnt, rlist1, rlist2, S0, aux);
    fatC<<<NT3 + NT1 + NT2 + NGATH, 256, 0, stream>>>(megaT, t1w2b, t2w2b, w2b3,
            cnt, rlist3, rel1c, rel2c, rel3c,
            S1c, S2c, pS3, tt0c, tt1c, tt2c);
    final_kernel<<<16, 256, 0, stream>>>(aux, targets, S0, S1c, S2c, pS3,
            tt0c, tt1c, tt2c, cidx1, cidx2, cidx3, (float*)d_out);
}

// Round 9
// 169.176 us; speedup vs baseline: 1.0896x; 1.0896x over previous
//
#include <hip/hip_runtime.h>
#include <hip/hip_bf16.h>
#include <math.h>

#define BB 2
#define SS 2048
#define DD 2048
#define NR (BB*(SS-1))      // 4094 valid rows
#define NRP 4096            // padded rows
#define MT_LD 768           // compact proj layout: [p1 512 | p2 128 | p3 32 | pad]
#define MT_P2 512
#define MT_P3 640

#define L2E 1.4426950408889634f
#define LN2F 0.6931471805599453f
#define LSE_SHIFT 4.0f
#define LSE_NC (-LSE_SHIFT * L2E)
#define WSCALE 16.0f        // fp8 weight pre-scale (avoids e4m3 subnormals at |w|~0.02)
#define WINV   0.0625f

typedef short  bh8   __attribute__((ext_vector_type(8)));
typedef float  f32x4 __attribute__((ext_vector_type(4)));
typedef long   l64x2 __attribute__((ext_vector_type(2)));   // 16 B = two fp8 MFMA operands

__device__ inline float bfl(unsigned short b) { return __uint_as_float(((unsigned)b) << 16); }
__device__ inline float expsh(float v) { return __builtin_amdgcn_exp2f(fmaf(v, L2E, LSE_NC)); }

__device__ inline float block_sum256(float v) {
    __shared__ float tmp[4];
    #pragma unroll
    for (int o = 32; o > 0; o >>= 1) v += __shfl_down(v, o, 64);
    int lane = threadIdx.x & 63, w = threadIdx.x >> 6;
    if (lane == 0) tmp[w] = v;
    __syncthreads();
    float r = tmp[0] + tmp[1] + tmp[2] + tmp[3];
    __syncthreads();
    return r;
}

// pack 4 floats -> 4 e4m3 bytes (HW cvt, saturating)
__device__ inline unsigned pack_fp8x4(float a, float b, float c, float d) {
    unsigned r = 0;
    r = __builtin_amdgcn_cvt_pk_fp8_f32(a, b, r, false);   // bytes 0-1
    r = __builtin_amdgcn_cvt_pk_fp8_f32(c, d, r, true);    // bytes 2-3
    return r;
}

// ================= stage A: LN + weight casts + compaction/init, ONE launch =================
struct CastSegs {
    const float* src[7];
    void* dst[7];
    int n_src[7];
    int n_tot[7];
    int b0[7];
    int isfp8[7];       // 1: fp8 e4m3 scaled by WSCALE; 0: bf16 scaled by scl[]
    float scl[7];       // bf16-path scale (1.0, or L2E for t3_w2 exp2-fold)
};
struct AParams {
    const float* x; const float* gamma; const float* beta;
    unsigned char* h8;                                 // fp8 h [4096][2048]
    CastSegs sg; int castBlocks;
    const int* targets;
    int *relH;
    int *cnt;                                          // [0]=n1 [1]=n2 [2]=n3 (memset 0)
    int *rlist1, *rlist2, *rlist3;                     // compact -> original row
    int *cidx1, *cidx2, *cidx3;                        // original row -> compact
    int *rel1c, *rel2c, *rel3c;                        // compact target cols
    float *S0, *S1c, *S2c, *out;
};

__global__ __launch_bounds__(256) void stageA(AParams p) {
    int blk = blockIdx.x, tid = threadIdx.x;
    if (blk < NRP) {                                   // ---- LayerNorm role -> fp8 h ----
        int n = blk;
        unsigned char* hr = p.h8 + (size_t)n * DD;
        if (n >= NR) { *(uint2*)(hr + tid * 8) = make_uint2(0,0); return; }
        int b = n / (SS - 1), t = n % (SS - 1);
        const float4* xr = (const float4*)(p.x + (size_t)(b * SS + t) * DD);
        float4 a = xr[tid * 2];
        float4 c = xr[tid * 2 + 1];
        float sum = a.x + a.y + a.z + a.w + c.x + c.y + c.z + c.w;
        sum = block_sum256(sum);
        float mu = sum * (1.0f / DD);
        float d[8] = {a.x-mu, a.y-mu, a.z-mu, a.w-mu, c.x-mu, c.y-mu, c.z-mu, c.w-mu};
        float sq = 0.f;
        #pragma unroll
        for (int i = 0; i < 8; ++i) sq += d[i] * d[i];
        sq = block_sum256(sq);
        float rstd = rsqrtf(sq * (1.0f / DD) + 1e-5f);
        const float4* g4 = (const float4*)p.gamma;
        const float4* be4 = (const float4*)p.beta;
        float4 g1 = g4[tid*2], g2 = g4[tid*2+1];
        float4 b1 = be4[tid*2], b2 = be4[tid*2+1];
        float gg[8] = {g1.x,g1.y,g1.z,g1.w,g2.x,g2.y,g2.z,g2.w};
        float bb[8] = {b1.x,b1.y,b1.z,b1.w,b2.x,b2.y,b2.z,b2.w};
        float o[8];
        #pragma unroll
        for (int i = 0; i < 8; ++i) o[i] = d[i] * rstd * gg[i] + bb[i];
        uint2 pk;
        pk.x = pack_fp8x4(o[0], o[1], o[2], o[3]);
        pk.y = pack_fp8x4(o[4], o[5], o[6], o[7]);
        *(uint2*)(hr + tid * 8) = pk;
        return;
    }
    blk -= NRP;
    if (blk < p.castBlocks) {                          // ---- weight cast role ----
        int k = 0;
        #pragma unroll
        for (int i = 1; i < 7; ++i) if (blk >= p.sg.b0[i]) k = i;
        int i4 = (blk - p.sg.b0[k]) * 1024 + tid * 4;
        if (i4 >= p.sg.n_tot[k]) return;
        float4 v = make_float4(0.f,0.f,0.f,0.f);
        if (i4 < p.sg.n_src[k]) v = *(const float4*)(p.sg.src[k] + i4);
        if (p.sg.isfp8[k]) {
            unsigned pk = pack_fp8x4(v.x * WSCALE, v.y * WSCALE, v.z * WSCALE, v.w * WSCALE);
            *(unsigned*)((unsigned char*)p.sg.dst[k] + i4) = pk;
        } else {
            float sc = p.sg.scl[k];
            __align__(8) __hip_bfloat16 o[4] = {
                __float2bfloat16(v.x * sc), __float2bfloat16(v.y * sc),
                __float2bfloat16(v.z * sc), __float2bfloat16(v.w * sc)};
            *(uint2*)((__hip_bfloat16*)p.sg.dst[k] + i4) = *(uint2*)o;
        }
        return;
    }
    blk -= p.castBlocks;                               // ---- init + compaction role ----
    int n = blk * 256 + tid;
    if (n >= NRP) return;
    int lbl = -1;
    if (n < NR) {
        int b = n / (SS - 1), t = n % (SS - 1);
        lbl = p.targets[b * SS + t + 1];
    }
    bool v = n < NR;
    p.relH[n] = v ? (lbl < 1000 ? lbl : 999) : -1;
    if (v) {                                           // compact per-cluster row lists
        if (lbl >= 1000 && lbl < 2000) {
            int ci = atomicAdd(&p.cnt[0], 1);
            p.rlist1[ci] = n; p.cidx1[n] = ci;
            int r1 = lbl - 1000; p.rel1c[ci] = r1 > 999 ? 999 : r1;
        } else if (lbl >= 2000 && lbl < 5000) {
            int ci = atomicAdd(&p.cnt[1], 1);
            p.rlist2[ci] = n; p.cidx2[n] = ci;
            int r2 = lbl - 2000; p.rel2c[ci] = r2 > 2999 ? 2999 : r2;
        } else if (lbl >= 5000) {
            int ci = atomicAdd(&p.cnt[2], 1);
            p.rlist3[ci] = n; p.cidx3[n] = ci;
            int r3 = lbl - 5000; p.rel3c[ci] = r3 > 26999 ? 26999 : r3;
        }
    }
    p.S0[n] = 0.f; p.S1c[n] = 0.f; p.S2c[n] = 0.f;
    if (n == 0) p.out[0] = 0.f;
}

// ================= stage B: mega GEMM fp8, 64x128 tile, BK=64, R6 loop verbatim ====
// T1 XCD swizzle on the HEAD sub-grid: bid<512 -> xcd=bid&7 owns y-band [8*xcd,8*xcd+8)
// x all 8 head panels. Per-XCD working set = A-band 1MB + head-W 2.1MB = 3.1MB, fits one
// XCD's 4MB L2 -> A fetched once chip-wide. Perfectly balanced (64 head blocks/XCD).
// Proj (bid>=512) keeps linear mapping: p1/p2 compact early-exit, p3 reads A once total.
__global__ __launch_bounds__(256) void megaF(
        const unsigned char* __restrict__ A,           // h8 [4096][2048] fp8
        const unsigned char* __restrict__ W,           // w1cat8 [1792][2048] fp8 (x16)
        __hip_bfloat16* __restrict__ megaT,            // [4096][768]
        const int* __restrict__ relH,
        const int* __restrict__ cnt,
        const int* __restrict__ rlist1, const int* __restrict__ rlist2,
        float* __restrict__ S0, float* __restrict__ aux) {
    __shared__ __align__(16) unsigned char smF[2][12288];   // [buf][As 4KB | Ws 8KB]
    int tid = threadIdx.x, wv = tid >> 6, lane = tid & 63;
    int bid = blockIdx.x, bx, by;
    if (bid < 512) {                                   // head: XCD-banded remap
        int xcd = bid & 7, slot = bid >> 3;            // slot in [0,64)
        bx = slot & 7;                                 // head panel 0..7
        by = xcd * 8 + (slot >> 3);                    // y-band [8*xcd, 8*xcd+8)
    } else {                                           // proj: linear
        int rem = bid - 512;
        bx = 8 + rem % 6;
        by = rem / 6;
    }
    int row0 = by * 64, col0 = bx * 128;
    const int* rl = nullptr; int nrow = NRP;
    if (bx >= 8 && bx < 12) { rl = rlist1; nrow = cnt[0]; if (row0 >= nrow) return; }
    else if (bx == 12)      { rl = rlist2; nrow = cnt[1]; if (row0 >= nrow) return; }
    int wrow = (wv >> 1) * 32, wcol = (wv & 1) * 64;
    f32x4 acc[2][4];
    #pragma unroll
    for (int i = 0; i < 2; ++i)
        #pragma unroll
        for (int j = 0; j < 4; ++j) acc[i][j] = (f32x4){0.f,0.f,0.f,0.f};
    int sr = lane >> 2;                                // row within 16-row chunk
    int kp = (((lane & 3) ^ (sr & 3)) * 16);           // swizzled byte slot within 64B row
    int mrow = lane & 15;
    int qx = (((lane >> 4) ^ (lane & 3)) * 16);        // swizzled frag b128 byte offset

    // hoisted per-lane A staging source (compact gather for p1/p2; identity otherwise)
    int ar = row0 + wv * 16 + sr;
    int orow = rl ? rl[ar < nrow ? ar : nrow - 1] : ar;
    const unsigned char* gabase = A + (size_t)orow * DD + kp;

    auto stage = [&](int buf, int k0) {
        {   // A: 4 chunks of 16 rows, one per wave
            void* la = (char*)&smF[buf][0] + wv * 1024 + lane * 16;
            __builtin_amdgcn_global_load_lds(
                (const __attribute__((address_space(1))) void*)(gabase + k0),
                (__attribute__((address_space(3))) void*)la, 16, 0, 0);
        }
        #pragma unroll
        for (int i = 0; i < 2; ++i) {                  // W: 8 chunks of 16 rows, two per wave
            int chunk = wv * 2 + i;
            int r = chunk * 16 + sr;
            const void* gw = W + (size_t)(col0 + r) * DD + k0 + kp;
            void* lw = (char*)&smF[buf][4096] + chunk * 1024 + lane * 16;
            __builtin_amdgcn_global_load_lds(
                (const __attribute__((address_space(1))) void*)gw,
                (__attribute__((address_space(3))) void*)lw, 16, 0, 0);
        }
    };

    stage(0, 0);
    asm volatile("s_waitcnt vmcnt(0)" ::: "memory");
    __builtin_amdgcn_s_barrier();
    __builtin_amdgcn_sched_barrier(0);
    int cur = 0;
    for (int k0 = 0; k0 < DD; k0 += 64) {
        if (k0 + 64 < DD) stage(cur ^ 1, k0 + 64);     // issue next tile early
        const unsigned char* As = &smF[cur][0];
        const unsigned char* Ws = &smF[cur][4096];
        l64x2 af[2], bfr[4];
        #pragma unroll
        for (int t = 0; t < 2; ++t)
            af[t]  = *(const l64x2*)(As + (wrow + t*16 + mrow) * 64 + qx);
        #pragma unroll
        for (int t = 0; t < 4; ++t)
            bfr[t] = *(const l64x2*)(Ws + (wcol + t*16 + mrow) * 64 + qx);
        #pragma unroll
        for (int s = 0; s < 2; ++s)
            #pragma unroll
            for (int i = 0; i < 2; ++i)
                #pragma unroll
                for (int j = 0; j < 4; ++j)
                    acc[i][j] = __builtin_amdgcn_mfma_f32_16x16x32_fp8_fp8(
                        af[i][s], bfr[j][s], acc[i][j], 0, 0, 0);
        asm volatile("s_waitcnt vmcnt(0) lgkmcnt(0)" ::: "memory");
        __builtin_amdgcn_s_barrier();
        __builtin_amdgcn_sched_barrier(0);
        cur ^= 1;
    }
    int ccol = lane & 15, g = lane >> 4;
    if (bx < 8) {                                      // ---- head: fused LSE, no store ----
        int grs[2][4], rh[2][4];
        float ps[2][4];
        #pragma unroll
        for (int i = 0; i < 2; ++i)
            #pragma unroll
            for (int r = 0; r < 4; ++r) {
                grs[i][r] = row0 + wrow + i*16 + g*4 + r;
                rh[i][r] = relH[grs[i][r]];
                ps[i][r] = 0.f;
            }
        #pragma unroll
        for (int i = 0; i < 2; ++i)
            #pragma unroll
            for (int j = 0; j < 4; ++j) {
                int gc = col0 + wcol + j*16 + ccol;
                bool inr = gc < 1003;
                #pragma unroll
                for (int r = 0; r < 4; ++r) {
                    float v = acc[i][j][r] * WINV;
                    if (gc == rh[i][r]) aux[grs[i][r]*8 + 0] = v;
                    if (gc >= 1000 && gc < 1003) aux[grs[i][r]*8 + 2 + (gc - 1000)] = v;
                    ps[i][r] += inr ? expsh(v) : 0.f;
                }
            }
        #pragma unroll
        for (int off = 1; off < 16; off <<= 1)         // reduce over the 16 ccol lanes
            #pragma unroll
            for (int i = 0; i < 2; ++i)
                #pragma unroll
                for (int r = 0; r < 4; ++r) ps[i][r] += __shfl_xor(ps[i][r], off, 64);
        if (ccol == 0)
            #pragma unroll
            for (int i = 0; i < 2; ++i)
                #pragma unroll
                for (int r = 0; r < 4; ++r) atomicAdd(&S0[grs[i][r]], ps[i][r]);
    } else {                                           // ---- proj: write megaT ----
        // rows are compact for p1/p2 (bx 8..12), original for p3 (bx 13) — same code.
        int cb = col0 - 1024 + wcol;
        #pragma unroll
        for (int i = 0; i < 2; ++i) {
            size_t gr0 = row0 + wrow + i*16 + g*4;
            #pragma unroll
            for (int j = 0; j < 4; ++j) {
                size_t gc = cb + j*16 + ccol;
                #pragma unroll
                for (int r = 0; r < 4; ++r)
                    megaT[(gr0 + r) * MT_LD + gc] = __float2bfloat16(acc[i][j][r] * WINV);
            }
        }
    }
}

// ================= tail GEMM — compact rows DIRECT (megaT p1/p2 segments are compact) =======
__device__ void tail_gemm(const __hip_bfloat16* A, int lda,
        const __hip_bfloat16* W, int K, int bx, int by, int validCols,
        const int* relc, float* S, float* tgt, char* sm, int nrows) {
    __hip_bfloat16* As = (__hip_bfloat16*)sm;          // 4 KB
    __hip_bfloat16* Ws = (__hip_bfloat16*)(sm + 4096); // 8 KB
    int tid = threadIdx.x, wv = tid >> 6, lane = tid & 63;
    int row0 = by * 64, col0 = bx * 128;
    int wrow = (wv >> 1) * 32, wcol = (wv & 1) * 64;
    f32x4 acc[2][4];
    #pragma unroll
    for (int i = 0; i < 2; ++i)
        #pragma unroll
        for (int j = 0; j < 4; ++j) acc[i][j] = (f32x4){0.f,0.f,0.f,0.f};
    int sr = lane >> 2;
    int sk = (((lane & 3) ^ (sr & 3)) * 8);            // swizzled k-slot (elements; 8 bf16 = 16B)
    int mrow = lane & 15;
    int qx = (((lane >> 4) ^ (lane & 3)) * 16);        // swizzled frag b128 byte offset

    for (int k0 = 0; k0 < K; k0 += 32) {
        __syncthreads();
        #pragma unroll
        for (int i = 0; i < 3; ++i) {
            int c = wv * 3 + i;
            const __hip_bfloat16* gsrc;
            char* ldst;
            if (c < 4) {
                gsrc = A + (size_t)(row0 + c * 16 + sr) * lda + k0 + sk;
                ldst = (char*)As + c * 1024 + lane * 16;
            } else {
                int cw = c - 4;
                gsrc = W + (size_t)(col0 + cw * 16 + sr) * K + k0 + sk;
                ldst = (char*)Ws + cw * 1024 + lane * 16;
            }
            __builtin_amdgcn_global_load_lds(
                (const __attribute__((address_space(1))) void*)gsrc,
                (__attribute__((address_space(3))) void*)ldst, 16, 0, 0);
        }
        __syncthreads();
        bh8 af[2], bfr[4];
        #pragma unroll
        for (int t = 0; t < 2; ++t)
            af[t] = *(const bh8*)((const char*)As + (wrow + t*16 + mrow) * 64 + qx);
        #pragma unroll
        for (int t = 0; t < 4; ++t)
            bfr[t] = *(const bh8*)((const char*)Ws + (wcol + t*16 + mrow) * 64 + qx);
        #pragma unroll
        for (int i = 0; i < 2; ++i)
            #pragma unroll
            for (int j = 0; j < 4; ++j)
                acc[i][j] = __builtin_amdgcn_mfma_f32_16x16x32_bf16(af[i], bfr[j], acc[i][j], 0, 0, 0);
    }
    int ccol = lane & 15, g = lane >> 4;
    int grs[2][4], rh[2][4];
    float p[2][4];
    #pragma unroll
    for (int i = 0; i < 2; ++i)
        #pragma unroll
        for (int r = 0; r < 4; ++r) {
            grs[i][r] = row0 + wrow + i*16 + g*4 + r;
            rh[i][r] = grs[i][r] < nrows ? relc[grs[i][r]] : 0;
            p[i][r] = 0.f;
        }
    #pragma unroll
    for (int i = 0; i < 2; ++i)
        #pragma unroll
        for (int j = 0; j < 4; ++j) {
            int gc = col0 + wcol + j*16 + ccol;
            bool inr = gc < validCols;
            #pragma unroll
            for (int r = 0; r < 4; ++r) {
                float v = acc[i][j][r];
                if (gc == rh[i][r] && grs[i][r] < nrows) tgt[grs[i][r]] = v;
                p[i][r] += inr ? expsh(v) : 0.f;
            }
        }
    #pragma unroll
    for (int off = 1; off < 16; off <<= 1)
        #pragma unroll
        for (int i = 0; i < 2; ++i)
            #pragma unroll
            for (int r = 0; r < 4; ++r) p[i][r] += __shfl_xor(p[i][r], off, 64);
    if (ccol == 0)
        #pragma unroll
        for (int i = 0; i < 2; ++i)
            #pragma unroll
            for (int r = 0; r < 4; ++r)
                if (grs[i][r] < nrows) atomicAdd(&S[grs[i][r]], p[i][r]);
}

// ================= t3 partial: compact rows, 16 colsplits, 4-deep register prefetch ========
#define T3_TILES 1688            // 1688*16 == 27008
#define T3_SPLIT 16
#define T3_TPC   106             // ceil(1688/16)
__device__ void t3_partial_body(const __hip_bfloat16* megaT,
        const __hip_bfloat16* w2b, float* pS, const int* rlist3, int n3,
        int idx, int tid, float* red /*[4][64]*/) {
    int rg = idx >> 4, cs = idx & 15;      // rowgroup (64 compact rows), colsplit
    int wv = tid >> 6, lane = tid & 63;
    int q = lane >> 4, cm = lane & 15;
    int row0 = rg * 64;
    bh8 af[4];
    #pragma unroll
    for (int h = 0; h < 4; ++h) {
        int r = row0 + h*16 + cm;
        int orow = rlist3[r < n3 ? r : n3 - 1];
        af[h] = *(const bh8*)(megaT + (size_t)orow * MT_LD + MT_P3 + q * 8);
    }
    int tile0 = cs * T3_TPC;
    int tile1 = tile0 + T3_TPC; if (tile1 > T3_TILES) tile1 = T3_TILES;
    float s[4][4];
    #pragma unroll
    for (int h = 0; h < 4; ++h)
        #pragma unroll
        for (int r = 0; r < 4; ++r) s[h][r] = 0.f;
    // 4-deep prefetch (covers ~2x L2 latency; clamped addrs, over-prefetch never consumed)
    int ot = tile0 + wv;
    auto baddr = [&](int t) {
        int tc = t < tile1 ? t : tile1 - 1;
        return (const bh8*)(w2b + (size_t)(tc * 16 + cm) * 32 + q * 8);
    };
    bh8 p0 = *baddr(ot), p1 = *baddr(ot + 4), p2 = *baddr(ot + 8), p3 = *baddr(ot + 12);
    for (; ot < tile1; ot += 4) {
        bh8 bcur = p0;
        p0 = p1; p1 = p2; p2 = p3;
        int otn = ot + 16;
        if (otn < tile1)
            p3 = *(const bh8*)(w2b + (size_t)(otn * 16 + cm) * 32 + q * 8);
        f32x4 c[4];
        #pragma unroll
        for (int h = 0; h < 4; ++h)
            c[h] = __builtin_amdgcn_mfma_f32_16x16x32_bf16(af[h], bcur, (f32x4){0,0,0,0}, 0, 0, 0);
        #pragma unroll
        for (int h = 0; h < 4; ++h)
            #pragma unroll
            for (int r = 0; r < 4; ++r) s[h][r] += __builtin_amdgcn_exp2f(c[h][r]);
    }
    #pragma unroll
    for (int off = 1; off < 16; off <<= 1)
        #pragma unroll
        for (int h = 0; h < 4; ++h)
            #pragma unroll
            for (int r = 0; r < 4; ++r) s[h][r] += __shfl_xor(s[h][r], off, 64);
    if (cm == 0)
        #pragma unroll
        for (int h = 0; h < 4; ++h)
            #pragma unroll
            for (int r = 0; r < 4; ++r)
                red[wv * 64 + h*16 + q*4 + r] = s[h][r];
    __syncthreads();
    if (tid < 64)
        pS[(size_t)(row0 + tid) * T3_SPLIT + cs] =
            red[tid] + red[64 + tid] + red[128 + tid] + red[192 + tid];
}

__device__ void t3_gather_body(const __hip_bfloat16* megaT, const __hip_bfloat16* w2b,
        const int* rlist3, const int* rel3c, int n3, float* tt2c, int idx, int tid) {
    int ci = idx * 256 + tid;
    if (ci >= n3) return;
    int orow = rlist3[ci];
    int rc = rel3c[ci];
    const unsigned short* pa = (const unsigned short*)(megaT + (size_t)orow * MT_LD + MT_P3);
    const unsigned short* pw = (const unsigned short*)(w2b + (size_t)rc * 32);
    float acc = 0.f;
    #pragma unroll
    for (int k = 0; k < 32; ++k) acc += bfl(pa[k]) * bfl(pw[k]);
    tt2c[ci] = acc;               // scaled by L2E (w2b pre-scaled); final multiplies by ln2
}

// ================= stage C: merged fat kernel, sequential roles, compact-row early-exit ======
#define NT3 (64 * T3_SPLIT)      // 1024 worst-case
#define NT1 512                  // worst-case
#define NT2 1536                 // worst-case
#define NGATH 16                 // worst-case
__global__ __launch_bounds__(256) void fatC(const __hip_bfloat16* __restrict__ megaT,
        const __hip_bfloat16* __restrict__ t1w2b, const __hip_bfloat16* __restrict__ t2w2b,
        const __hip_bfloat16* __restrict__ w2b3,
        const int* __restrict__ cnt,
        const int* __restrict__ rlist3,
        const int* __restrict__ rel1c, const int* __restrict__ rel2c, const int* __restrict__ rel3c,
        float* __restrict__ S1c, float* __restrict__ S2c, float* __restrict__ pS3,
        float* __restrict__ tt0c, float* __restrict__ tt1c, float* __restrict__ tt2c) {
    __shared__ __align__(16) char sm[12288];
    int idx = blockIdx.x, tid = threadIdx.x;
    if (idx < NT3) {                                   // ---- t3 partial sums ----
        int n3 = cnt[2];
        if ((idx >> 4) * 64 >= n3) return;             // early-exit past compact rows
        t3_partial_body(megaT, w2b3, pS3, rlist3, n3, idx, tid, (float*)sm);
        return;
    }
    idx -= NT3;
    if (idx < NT1) {                                   // ---- t1 (compact rows ~128) ----
        int n1 = cnt[0];
        int by = idx / 8, bx = idx % 8;
        if (by * 64 >= n1) return;
        tail_gemm(megaT, MT_LD, t1w2b, 512, bx, by, 1000, rel1c, S1c, tt0c, sm, n1);
        return;
    }
    idx -= NT1;
    if (idx < NT2) {                                   // ---- t2 (compact rows ~384) ----
        int n2 = cnt[1];
        int by = idx / 24, bx = idx % 24;
        if (by * 64 >= n2) return;
        tail_gemm(megaT + MT_P2, MT_LD, t2w2b, 128, bx, by, 3000, rel2c, S2c, tt1c, sm, n2);
        return;
    }
    idx -= NT2;
    t3_gather_body(megaT, w2b3, rlist3, rel3c, cnt[2], tt2c, idx, tid);
}

// ================= stage E: final assembly =================
__global__ __launch_bounds__(256) void final_kernel(const float* __restrict__ aux,
        const int* __restrict__ targets,
        const float* __restrict__ S0, const float* __restrict__ S1c, const float* __restrict__ S2c,
        const float* __restrict__ pS3,
        const float* __restrict__ tt0c, const float* __restrict__ tt1c, const float* __restrict__ tt2c,
        const int* __restrict__ cidx1, const int* __restrict__ cidx2, const int* __restrict__ cidx3,
        float* __restrict__ out) {
    int n = blockIdx.x * 256 + threadIdx.x;
    float local = 0.f;
    if (n < NR) {
        int b = n / (SS - 1), t = n % (SS - 1);
        int lbl = targets[b * SS + t + 1];
        float lse = logf(S0[n]) + LSE_SHIFT;
        float o;
        if (lbl < 1000)      o = aux[n*8 + 0] - lse;
        else if (lbl < 2000) {
            int ci = cidx1[n];
            o = (aux[n*8 + 2] - lse) + (tt0c[ci] - (logf(S1c[ci]) + LSE_SHIFT));
        } else if (lbl < 5000) {
            int ci = cidx2[n];
            o = (aux[n*8 + 3] - lse) + (tt1c[ci] - (logf(S2c[ci]) + LSE_SHIFT));
        } else {
            int ci = cidx3[n];
            float S3 = 0.f;
            const float4* p4 = (const float4*)(pS3 + (size_t)ci * T3_SPLIT);
            #pragma unroll
            for (int c = 0; c < T3_SPLIT/4; ++c) {
                float4 v = p4[c];
                S3 += v.x + v.y + v.z + v.w;
            }
            S3 -= 8.0f;                                // pad cols: logit 0 -> exp2(0)=1 each
            o = (aux[n*8 + 4] - lse) + (tt2c[ci] * LN2F - logf(S3));
        }
        local = o;
    }
    local = block_sum256(local);
    if (threadIdx.x == 0) atomicAdd(out, -local / (float)NR);
}

extern "C" void kernel_launch(void* const* d_in, const int* in_sizes, int n_in,
                              void* d_out, int out_size, void* d_ws, size_t ws_size,
                              hipStream_t stream) {
    const float* x      = (const float*)d_in[0];
    const int*   targets= (const int*)d_in[1];
    const float* gamma  = (const float*)d_in[2];
    const float* beta   = (const float*)d_in[3];
    const float* head_w = (const float*)d_in[4];
    const float* t1_w1  = (const float*)d_in[5];
    const float* t1_w2  = (const float*)d_in[6];
    const float* t2_w1  = (const float*)d_in[7];
    const float* t2_w2  = (const float*)d_in[8];
    const float* t3_w1  = (const float*)d_in[9];
    const float* t3_w2  = (const float*)d_in[10];
    (void)in_sizes; (void)n_in; (void)out_size; (void)ws_size;

    char* base = (char*)d_ws;
    size_t off = 0;
    auto ab = [&](size_t nbytes) { char* p = base + off; off += (nbytes + 15) & ~(size_t)15; return p; };
    unsigned char* h8     = (unsigned char*)ab((size_t)NRP * DD);              // 8.4 MB fp8
    unsigned char* w1cat8 = (unsigned char*)ab((size_t)1792 * DD);             // 3.7 MB fp8
    __hip_bfloat16* megaT = (__hip_bfloat16*)ab((size_t)NRP * MT_LD * 2);      // 6.3 MB
    __hip_bfloat16* t1w2b = (__hip_bfloat16*)ab((size_t)1024 * 512 * 2);
    __hip_bfloat16* t2w2b = (__hip_bfloat16*)ab((size_t)3072 * 128 * 2);
    __hip_bfloat16* w2b3  = (__hip_bfloat16*)ab((size_t)27008 * 32 * 2);
    float* aux = (float*)ab((size_t)NRP * 8 * 4);
    float* pS3 = (float*)ab((size_t)NRP * T3_SPLIT * 4);
    float* S0  = (float*)ab(NRP * 4);
    float* S1c = (float*)ab(NRP * 4);
    float* S2c = (float*)ab(NRP * 4);
    int* relH  = (int*)ab(NRP * 4);
    int* cnt   = (int*)ab(4 * 4);
    int* rlist1= (int*)ab(NRP * 4);
    int* rlist2= (int*)ab(NRP * 4);
    int* rlist3= (int*)ab(NRP * 4);
    int* cidx1 = (int*)ab(NRP * 4);
    int* cidx2 = (int*)ab(NRP * 4);
    int* cidx3 = (int*)ab(NRP * 4);
    int* rel1c = (int*)ab(NRP * 4);
    int* rel2c = (int*)ab(NRP * 4);
    int* rel3c = (int*)ab(NRP * 4);
    float* tt0c= (float*)ab(NRP * 4);
    float* tt1c= (float*)ab(NRP * 4);
    float* tt2c= (float*)ab(NRP * 4);

    hipMemsetAsync(cnt, 0, 4 * 4, stream);             // zero compaction counters

    AParams p;
    p.x = x; p.gamma = gamma; p.beta = beta; p.h8 = h8;
    p.targets = targets;
    p.relH = relH;
    p.cnt = cnt;
    p.rlist1 = rlist1; p.rlist2 = rlist2; p.rlist3 = rlist3;
    p.cidx1 = cidx1; p.cidx2 = cidx2; p.cidx3 = cidx3;
    p.rel1c = rel1c; p.rel2c = rel2c; p.rel3c = rel3c;
    p.S0 = S0; p.S1c = S1c; p.S2c = S2c; p.out = (float*)d_out;
    const float* srcs[7] = {head_w, t1_w1, t2_w1, t3_w1, t1_w2, t2_w2, t3_w2};
    void* dsts[7] = {w1cat8, w1cat8 + (size_t)1024*2048, w1cat8 + (size_t)1536*2048,
                     w1cat8 + (size_t)1664*2048, t1w2b, t2w2b, w2b3};
    int nsrc[7] = {1003*2048, 512*2048, 128*2048, 32*2048, 1000*512, 3000*128, 27000*32};
    int ntot[7] = {1024*2048, 512*2048, 128*2048, 128*2048, 1024*512, 3072*128, 27008*32};
    int isf8[7] = {1, 1, 1, 1, 0, 0, 0};
    float scls[7] = {1.f, 1.f, 1.f, 1.f, 1.0f, 1.0f, L2E};   // t3_w2 pre-scaled for exp2-direct
    int blk = 0;
    for (int i = 0; i < 7; ++i) {
        p.sg.src[i] = srcs[i]; p.sg.dst[i] = dsts[i];
        p.sg.n_src[i] = nsrc[i]; p.sg.n_tot[i] = ntot[i];
        p.sg.isfp8[i] = isf8[i];
        p.sg.scl[i] = scls[i];
        p.sg.b0[i] = blk;
        blk += (ntot[i] + 1023) / 1024;
    }
    p.castBlocks = blk;

    stageA<<<NRP + blk + 16, 256, 0, stream>>>(p);
    megaF<<<896, 256, 0, stream>>>(h8, w1cat8, megaT, relH, cnt, rlist1, rlist2, S0, aux);
    fatC<<<NT3 + NT1 + NT2 + NGATH, 256, 0, stream>>>(megaT, t1w2b, t2w2b, w2b3,
            cnt, rlist3, rel1c, rel2c, rel3c,
            S1c, S2c, pS3, tt0c, tt1c, tt2c);
    final_kernel<<<16, 256, 0, stream>>>(aux, targets, S0, S1c, S2c, pS3,
            tt0c, tt1c, tt2c, cidx1, cidx2, cidx3, (float*)d_out);
}